// Round 1
// baseline (1576.635 us; speedup 1.0000x reference)
//
#include <hip/hip_runtime.h>
#include <math.h>

// Problem constants
constexpr int cH  = 768;
constexpr int cDM = 1536;
constexpr int cN  = 16;
constexpr int cR  = 48;
constexpr int cB  = 2;
constexpr int cL  = 1024;
constexpr int cP  = 80;   // R + 2N

// ---------------------------------------------------------------------------
// Generic NT GEMM: C[m][n] = sum_k A[m][k] * Bt[n][k]
// A: M x K (row stride lda), Bt: N2 x K (row stride ldb), C: M x N2 (ldc)
// Batched via grid.z with strides sA/sB/sC.
// splitRow: if C1 != nullptr and m >= splitRow, write to C1 at row m-splitRow.
// epi==1: v = softplus(v + bias[m])
// Requires: M % 64 == 0, K % 16 == 0, lda/ldb % 4 == 0. N2 arbitrary.
// ---------------------------------------------------------------------------
__global__ __launch_bounds__(256)
void gemm_nt(const float* __restrict__ A, const float* __restrict__ Bt,
             float* __restrict__ C0, float* __restrict__ C1,
             const float* __restrict__ bias,
             int M, int N2, int Kd, int lda, int ldb, int ldc,
             long sA, long sB, long sC, int splitRow, int epi)
{
    __shared__ float As[16][68];
    __shared__ float Bs[16][68];
    const int tid = threadIdx.x;
    const int bz  = blockIdx.z;
    const int n0  = blockIdx.x * 64;
    const int m0  = blockIdx.y * 64;
    const float* Ab = A + (long)bz * sA;
    const float* Bb = Bt + (long)bz * sB;
    const int tx = tid & 15, ty = tid >> 4;
    const int lr = tid >> 2;          // 0..63: tile row loaded by this thread
    const int lk = (tid & 3) << 2;    // 0,4,8,12: k offset (float4)

    float acc[4][4] = {};

    for (int k0 = 0; k0 < Kd; k0 += 16) {
        float4 av = *(const float4*)(Ab + (long)(m0 + lr) * lda + k0 + lk);
        float4 bv = make_float4(0.f, 0.f, 0.f, 0.f);
        const int nr = n0 + lr;
        if (nr < N2) bv = *(const float4*)(Bb + (long)nr * ldb + k0 + lk);
        __syncthreads();
        As[lk + 0][lr] = av.x; As[lk + 1][lr] = av.y;
        As[lk + 2][lr] = av.z; As[lk + 3][lr] = av.w;
        Bs[lk + 0][lr] = bv.x; Bs[lk + 1][lr] = bv.y;
        Bs[lk + 2][lr] = bv.z; Bs[lk + 3][lr] = bv.w;
        __syncthreads();
        #pragma unroll
        for (int kk = 0; kk < 16; ++kk) {
            const float4 a4 = *(const float4*)&As[kk][ty * 4];
            const float4 b4 = *(const float4*)&Bs[kk][tx * 4];
            const float a[4] = {a4.x, a4.y, a4.z, a4.w};
            const float b[4] = {b4.x, b4.y, b4.z, b4.w};
            #pragma unroll
            for (int i = 0; i < 4; ++i)
                #pragma unroll
                for (int j = 0; j < 4; ++j)
                    acc[i][j] = fmaf(a[i], b[j], acc[i][j]);
        }
    }

    #pragma unroll
    for (int i = 0; i < 4; ++i) {
        const int m = m0 + ty * 4 + i;
        float* crow;
        if (C1 != nullptr && m >= splitRow)
            crow = C1 + (long)bz * sC + (long)(m - splitRow) * ldc;
        else
            crow = C0 + (long)bz * sC + (long)m * ldc;
        const float bi = (epi == 1) ? bias[m] : 0.f;
        #pragma unroll
        for (int j = 0; j < 4; ++j) {
            const int n = n0 + tx * 4 + j;
            if (n < N2) {
                float v = acc[i][j];
                if (epi == 1) {
                    const float t = v + bi;
                    v = fmaxf(t, 0.f) + log1pf(__expf(-fabsf(t)));  // stable softplus
                }
                crow[n] = v;
            }
        }
    }
}

// ---------------------------------------------------------------------------
// Depthwise causal conv (K=4) + bias + SiLU. Writes both (b,d,l) and (b,l,d).
// ---------------------------------------------------------------------------
__global__ __launch_bounds__(256)
void conv_silu_kernel(const float* __restrict__ x, const float* __restrict__ cw,
                      const float* __restrict__ cb,
                      float* __restrict__ conv, float* __restrict__ convT)
{
    const int l = blockIdx.x * 256 + threadIdx.x;
    const int d = blockIdx.y;
    const int b = blockIdx.z;
    const float* xr = x + ((long)b * cDM + d) * cL;
    const float w0 = cw[d * 4 + 0], w1 = cw[d * 4 + 1];
    const float w2 = cw[d * 4 + 2], w3 = cw[d * 4 + 3];
    float v = cb[d] + w3 * xr[l];
    if (l >= 1) v = fmaf(w2, xr[l - 1], v);
    if (l >= 2) v = fmaf(w1, xr[l - 2], v);
    if (l >= 3) v = fmaf(w0, xr[l - 3], v);
    const float s = v / (1.f + __expf(-v));   // SiLU
    conv[((long)b * cDM + d) * cL + l] = s;
    convT[((long)b * cL + l) * cDM + d] = s;
}

// ---------------------------------------------------------------------------
// Selective scan. One 16-lane group per channel d (lane = state index n).
// DIR=+1: l = 0..L-1, writes ysum. DIR=-1: l = L-1..0, accumulates into ysum.
// ysum layout: (b, l, d).
// ---------------------------------------------------------------------------
template<int DIR>
__global__ __launch_bounds__(256)
void scan_kernel(const float* __restrict__ conv,   // (B,DM,L)  u
                 const float* __restrict__ gate,   // (B,DM,L)
                 const float* __restrict__ delta,  // (B,DM,L)
                 const float* __restrict__ ssm,    // (B,L,80): B at 48+n, C at 64+n
                 const float* __restrict__ Alog,   // (DM,16)
                 const float* __restrict__ Dp,     // (DM)
                 float* __restrict__ ysum)         // (B,L,DM)
{
    const int g = threadIdx.x >> 4;   // group within block: 16 channels/block
    const int n = threadIdx.x & 15;   // state index
    const int d = blockIdx.x * 16 + g;
    const int b = blockIdx.y;

    const float a  = -__expf(Alog[d * cN + n]);
    const float Dd = Dp[d];
    const float* up = conv  + ((long)b * cDM + d) * cL;
    const float* gp = gate  + ((long)b * cDM + d) * cL;
    const float* dp = delta + ((long)b * cDM + d) * cL;
    const float* sp = ssm + (long)b * cL * cP;

    float xs = 0.f;
    for (int t = 0; t < cL; ++t) {
        const int l = (DIR > 0) ? t : (cL - 1 - t);
        const float du = dp[l];
        const float u  = up[l];
        const float Bn = sp[l * cP + cR + n];
        const float Cn = sp[l * cP + cR + cN + n];
        const float dA = __expf(du * a);
        xs = fmaf(dA, xs, (du * u) * Bn);
        float y = xs * Cn;
        y += __shfl_xor(y, 1);
        y += __shfl_xor(y, 2);
        y += __shfl_xor(y, 4);
        y += __shfl_xor(y, 8);
        if (n == 0) {
            const float gv  = gp[l];
            const float val = (y + u * Dd) * (gv / (1.f + __expf(-gv)));
            float* o = ysum + ((long)b * cL + l) * cDM + d;
            if (DIR > 0) *o = val; else *o += val;
        }
    }
}

// ---------------------------------------------------------------------------
extern "C" void kernel_launch(void* const* d_in, const int* in_sizes, int n_in,
                              void* d_out, int out_size, void* d_ws, size_t ws_size,
                              hipStream_t stream)
{
    const float* hid   = (const float*)d_in[0];   // (B,L,H)
    const float* inw   = (const float*)d_in[1];   // (2DM,H)
    const float* convw = (const float*)d_in[2];   // (DM,K)
    const float* convb = (const float*)d_in[3];   // (DM)
    const float* xpw   = (const float*)d_in[4];   // (80,DM)
    const float* dtw   = (const float*)d_in[5];   // (DM,R)
    const float* dtb   = (const float*)d_in[6];   // (DM)
    const float* xpbw  = (const float*)d_in[7];
    const float* dtbw  = (const float*)d_in[8];
    const float* dtbb  = (const float*)d_in[9];
    const float* Alog  = (const float*)d_in[10];  // (DM,16)
    const float* Alogb = (const float*)d_in[11];
    const float* Dv    = (const float*)d_in[12];
    const float* Dbv   = (const float*)d_in[13];
    const float* outw  = (const float*)d_in[14];  // (H,DM)
    float* out = (float*)d_out;                   // (B,L,H)

    float* ws = (float*)d_ws;
    const long S = (long)cB * cDM * cL;           // 3,145,728 floats
    float* xbuf   = ws;            // x; later reused as delta_f
    float* gate   = ws + S;
    float* conv   = ws + 2 * S;    // u (b,d,l)
    float* convT  = ws + 3 * S;    // (b,l,d); later reused as ysum
    float* deltab = ws + 4 * S;
    float* ssmf   = ws + 5 * S;                   // (B,L,80)
    float* ssmb   = ssmf + (long)cB * cL * cP;

    const dim3 blk(256);

    // 1. in_proj: proj[b][p][l] = sum_h W[p][h]*hid[b][l][h]; split x / gate
    gemm_nt<<<dim3(cL / 64, (2 * cDM) / 64, cB), blk, 0, stream>>>(
        inw, hid, xbuf, gate, nullptr,
        2 * cDM, cL, cH, cH, cH, cL,
        0L, (long)cL * cH, (long)cDM * cL, cDM, 0);

    // 2. causal conv + SiLU (+ transpose copy)
    conv_silu_kernel<<<dim3(cL / 256, cDM, cB), blk, 0, stream>>>(
        xbuf, convw, convb, conv, convT);

    // 3. x_proj fwd: ssm_f[b][l][p] = sum_d convT[b][l][d]*xpw[p][d]
    gemm_nt<<<dim3((cP + 63) / 64, cL / 64, cB), blk, 0, stream>>>(
        convT, xpw, ssmf, nullptr, nullptr,
        cL, cP, cDM, cDM, cDM, cP,
        (long)cL * cDM, 0L, (long)cL * cP, 0, 0);

    // 4. x_proj bwd (normal order; reversal handled by scan traversal)
    gemm_nt<<<dim3((cP + 63) / 64, cL / 64, cB), blk, 0, stream>>>(
        convT, xpbw, ssmb, nullptr, nullptr,
        cL, cP, cDM, cDM, cDM, cP,
        (long)cL * cDM, 0L, (long)cL * cP, 0, 0);

    // 5. delta fwd: delta[b][d][l] = softplus(sum_r dtw[d][r]*ssm_f[b][l][r] + dtb[d])
    gemm_nt<<<dim3(cL / 64, cDM / 64, cB), blk, 0, stream>>>(
        dtw, ssmf, xbuf /*delta_f*/, nullptr, dtb,
        cDM, cL, cR, cR, cP, cL,
        0L, (long)cL * cP, (long)cDM * cL, 0, 1);

    // 6. delta bwd
    gemm_nt<<<dim3(cL / 64, cDM / 64, cB), blk, 0, stream>>>(
        dtbw, ssmb, deltab, nullptr, dtbb,
        cDM, cL, cR, cR, cP, cL,
        0L, (long)cL * cP, (long)cDM * cL, 0, 1);

    // 7. forward scan (writes ysum)
    scan_kernel<1><<<dim3(cDM / 16, cB), blk, 0, stream>>>(
        conv, gate, xbuf, ssmf, Alog, Dv, convT /*ysum*/);

    // 8. backward scan (accumulates into ysum)
    scan_kernel<-1><<<dim3(cDM / 16, cB), blk, 0, stream>>>(
        conv, gate, deltab, ssmb, Alogb, Dbv, convT);

    // 9. out_proj: out[b][l][h] = sum_d ysum[b][l][d]*outw[h][d]
    gemm_nt<<<dim3(cH / 64, cL / 64, cB), blk, 0, stream>>>(
        convT, outw, out, nullptr, nullptr,
        cL, cH, cDM, cDM, cDM, cH,
        (long)cL * cDM, 0L, (long)cL * cH, 0, 0);
}

// Round 2
// 645.340 us; speedup vs baseline: 2.4431x; 2.4431x over previous
//
#include <hip/hip_runtime.h>
#include <math.h>

// Problem constants
constexpr int cH  = 768;
constexpr int cDM = 1536;
constexpr int cN  = 16;
constexpr int cR  = 48;
constexpr int cB  = 2;
constexpr int cL  = 1024;
constexpr int cP  = 80;   // R + 2N

// ---------------------------------------------------------------------------
// Generic NT GEMM: C[m][n] = sum_k A[m][k] * Bt[n][k]
// A: M x K (row stride lda), Bt: N2 x K (row stride ldb), C: M x N2 (ldc)
// Batched via grid.z with strides sA/sB/sC.
// splitRow: if C1 != nullptr and m >= splitRow, write to C1 at row m-splitRow.
// epi==1: v = softplus(v + bias[m])
// Requires: M % 64 == 0, K % 16 == 0, lda/ldb % 4 == 0. N2 arbitrary.
// ---------------------------------------------------------------------------
__global__ __launch_bounds__(256)
void gemm_nt(const float* __restrict__ A, const float* __restrict__ Bt,
             float* __restrict__ C0, float* __restrict__ C1,
             const float* __restrict__ bias,
             int M, int N2, int Kd, int lda, int ldb, int ldc,
             long sA, long sB, long sC, int splitRow, int epi)
{
    __shared__ float As[16][68];
    __shared__ float Bs[16][68];
    const int tid = threadIdx.x;
    const int bz  = blockIdx.z;
    const int n0  = blockIdx.x * 64;
    const int m0  = blockIdx.y * 64;
    const float* Ab = A + (long)bz * sA;
    const float* Bb = Bt + (long)bz * sB;
    const int tx = tid & 15, ty = tid >> 4;
    const int lr = tid >> 2;          // 0..63: tile row loaded by this thread
    const int lk = (tid & 3) << 2;    // 0,4,8,12: k offset (float4)

    float acc[4][4] = {};

    for (int k0 = 0; k0 < Kd; k0 += 16) {
        float4 av = *(const float4*)(Ab + (long)(m0 + lr) * lda + k0 + lk);
        float4 bv = make_float4(0.f, 0.f, 0.f, 0.f);
        const int nr = n0 + lr;
        if (nr < N2) bv = *(const float4*)(Bb + (long)nr * ldb + k0 + lk);
        __syncthreads();
        As[lk + 0][lr] = av.x; As[lk + 1][lr] = av.y;
        As[lk + 2][lr] = av.z; As[lk + 3][lr] = av.w;
        Bs[lk + 0][lr] = bv.x; Bs[lk + 1][lr] = bv.y;
        Bs[lk + 2][lr] = bv.z; Bs[lk + 3][lr] = bv.w;
        __syncthreads();
        #pragma unroll
        for (int kk = 0; kk < 16; ++kk) {
            const float4 a4 = *(const float4*)&As[kk][ty * 4];
            const float4 b4 = *(const float4*)&Bs[kk][tx * 4];
            const float a[4] = {a4.x, a4.y, a4.z, a4.w};
            const float b[4] = {b4.x, b4.y, b4.z, b4.w};
            #pragma unroll
            for (int i = 0; i < 4; ++i)
                #pragma unroll
                for (int j = 0; j < 4; ++j)
                    acc[i][j] = fmaf(a[i], b[j], acc[i][j]);
        }
    }

    #pragma unroll
    for (int i = 0; i < 4; ++i) {
        const int m = m0 + ty * 4 + i;
        float* crow;
        if (C1 != nullptr && m >= splitRow)
            crow = C1 + (long)bz * sC + (long)(m - splitRow) * ldc;
        else
            crow = C0 + (long)bz * sC + (long)m * ldc;
        const float bi = (epi == 1) ? bias[m] : 0.f;
        #pragma unroll
        for (int j = 0; j < 4; ++j) {
            const int n = n0 + tx * 4 + j;
            if (n < N2) {
                float v = acc[i][j];
                if (epi == 1) {
                    const float t = v + bi;
                    v = fmaxf(t, 0.f) + log1pf(__expf(-fabsf(t)));  // stable softplus
                }
                crow[n] = v;
            }
        }
    }
}

// ---------------------------------------------------------------------------
// Depthwise causal conv (K=4) + bias + SiLU. Writes both (b,d,l) and (b,l,d).
// ---------------------------------------------------------------------------
__global__ __launch_bounds__(256)
void conv_silu_kernel(const float* __restrict__ x, const float* __restrict__ cw,
                      const float* __restrict__ cb,
                      float* __restrict__ conv, float* __restrict__ convT)
{
    const int l = blockIdx.x * 256 + threadIdx.x;
    const int d = blockIdx.y;
    const int b = blockIdx.z;
    const float* xr = x + ((long)b * cDM + d) * cL;
    const float w0 = cw[d * 4 + 0], w1 = cw[d * 4 + 1];
    const float w2 = cw[d * 4 + 2], w3 = cw[d * 4 + 3];
    float v = cb[d] + w3 * xr[l];
    if (l >= 1) v = fmaf(w2, xr[l - 1], v);
    if (l >= 2) v = fmaf(w1, xr[l - 2], v);
    if (l >= 3) v = fmaf(w0, xr[l - 3], v);
    const float s = v / (1.f + __expf(-v));   // SiLU
    conv[((long)b * cDM + d) * cL + l] = s;
    convT[((long)b * cL + l) * cDM + d] = s;
}

// ---------------------------------------------------------------------------
// Fused bidirectional selective scan.
// grid = (DM/16, B, 2):  blockIdx.z = 0 fwd, 1 bwd.
// One 16-lane group per channel d (lane = state index n).
// Chunked (16 steps): all loads + exp/shuffle precompute hoisted off the
// serial chain; recurrence is 16 back-to-back fmaf. Both directions
// atomicAdd into zero-inited ysum (2 commutative adds/address -> determ.)
// ---------------------------------------------------------------------------
__global__ __launch_bounds__(256)
void scan2_kernel(const float* __restrict__ conv,     // (B,DM,L)  u
                  const float* __restrict__ gate,     // (B,DM,L)
                  const float* __restrict__ delta_f,  // (B,DM,L)
                  const float* __restrict__ delta_b,
                  const float* __restrict__ ssm_f,    // (B,L,80)
                  const float* __restrict__ ssm_b,
                  const float* __restrict__ Alog_f,   // (DM,16)
                  const float* __restrict__ Alog_b,
                  const float* __restrict__ D_f,      // (DM)
                  const float* __restrict__ D_b,
                  float* __restrict__ ysum)           // (B,L,DM) zero-inited
{
    const int g = threadIdx.x >> 4;   // group within block
    const int n = threadIdx.x & 15;   // state index
    const int d = blockIdx.x * 16 + g;
    const int b = blockIdx.y;
    const int dir = blockIdx.z;       // 0 = fwd, 1 = bwd

    const float* delta = dir ? delta_b : delta_f;
    const float* ssm   = dir ? ssm_b   : ssm_f;
    const float* Alog  = dir ? Alog_b  : Alog_f;
    const float  Dd    = dir ? D_b[d]  : D_f[d];
    const float  a     = -__expf(Alog[d * cN + n]);

    const float* up = conv  + ((long)b * cDM + d) * cL;
    const float* gp = gate  + ((long)b * cDM + d) * cL;
    const float* dp = delta + ((long)b * cDM + d) * cL;
    const float* sp = ssm + (long)b * cL * cP;

    float xs = 0.f;
    for (int c = 0; c < cL / 16; ++c) {
        const int l0 = dir ? (cL - 1 - c * 16) : (c * 16);
        const int ln = dir ? (l0 - n) : (l0 + n);   // lane's own position
        const float du_n = dp[ln];
        const float u_n  = up[ln];
        const float gv_n = gp[ln];

        float dA[16], dBu[16], Ct[16];
        #pragma unroll
        for (int t = 0; t < 16; ++t) {
            const int lt = dir ? (l0 - t) : (l0 + t);
            const float Bt = sp[lt * cP + cR + n];
            Ct[t] = sp[lt * cP + cR + cN + n];
            const float dut = __shfl(du_n, t, 16);
            const float ut  = __shfl(u_n,  t, 16);
            dA[t]  = __expf(dut * a);
            dBu[t] = (dut * ut) * Bt;
        }

        float yo = 0.f;
        #pragma unroll
        for (int t = 0; t < 16; ++t) {
            xs = fmaf(dA[t], xs, dBu[t]);     // the only serial dependence
            float y = xs * Ct[t];
            y += __shfl_xor(y, 1);
            y += __shfl_xor(y, 2);
            y += __shfl_xor(y, 4);
            y += __shfl_xor(y, 8);
            if (n == t) yo = y;               // lane t keeps step t's sum
        }

        const float val = (yo + u_n * Dd) * (gv_n / (1.f + __expf(-gv_n)));
        atomicAdd(&ysum[((long)b * cL + ln) * cDM + d], val);
    }
}

// ---------------------------------------------------------------------------
extern "C" void kernel_launch(void* const* d_in, const int* in_sizes, int n_in,
                              void* d_out, int out_size, void* d_ws, size_t ws_size,
                              hipStream_t stream)
{
    const float* hid   = (const float*)d_in[0];   // (B,L,H)
    const float* inw   = (const float*)d_in[1];   // (2DM,H)
    const float* convw = (const float*)d_in[2];   // (DM,K)
    const float* convb = (const float*)d_in[3];   // (DM)
    const float* xpw   = (const float*)d_in[4];   // (80,DM)
    const float* dtw   = (const float*)d_in[5];   // (DM,R)
    const float* dtb   = (const float*)d_in[6];   // (DM)
    const float* xpbw  = (const float*)d_in[7];
    const float* dtbw  = (const float*)d_in[8];
    const float* dtbb  = (const float*)d_in[9];
    const float* Alog  = (const float*)d_in[10];  // (DM,16)
    const float* Alogb = (const float*)d_in[11];
    const float* Dv    = (const float*)d_in[12];
    const float* Dbv   = (const float*)d_in[13];
    const float* outw  = (const float*)d_in[14];  // (H,DM)
    float* out = (float*)d_out;                   // (B,L,H)

    float* ws = (float*)d_ws;
    const long S = (long)cB * cDM * cL;           // 3,145,728 floats
    float* xbuf   = ws;            // x; later reused as delta_f
    float* gate   = ws + S;
    float* conv   = ws + 2 * S;    // u (b,d,l)
    float* convT  = ws + 3 * S;    // (b,l,d); later reused as ysum
    float* deltab = ws + 4 * S;
    float* ssmf   = ws + 5 * S;                   // (B,L,80)
    float* ssmb   = ssmf + (long)cB * cL * cP;

    const dim3 blk(256);

    // 1. in_proj: proj[b][p][l] = sum_h W[p][h]*hid[b][l][h]; split x / gate
    gemm_nt<<<dim3(cL / 64, (2 * cDM) / 64, cB), blk, 0, stream>>>(
        inw, hid, xbuf, gate, nullptr,
        2 * cDM, cL, cH, cH, cH, cL,
        0L, (long)cL * cH, (long)cDM * cL, cDM, 0);

    // 2. causal conv + SiLU (+ transpose copy)
    conv_silu_kernel<<<dim3(cL / 256, cDM, cB), blk, 0, stream>>>(
        xbuf, convw, convb, conv, convT);

    // 3. x_proj fwd: ssm_f[b][l][p] = sum_d convT[b][l][d]*xpw[p][d]
    gemm_nt<<<dim3((cP + 63) / 64, cL / 64, cB), blk, 0, stream>>>(
        convT, xpw, ssmf, nullptr, nullptr,
        cL, cP, cDM, cDM, cDM, cP,
        (long)cL * cDM, 0L, (long)cL * cP, 0, 0);

    // 4. x_proj bwd (normal order; reversal handled by scan traversal)
    gemm_nt<<<dim3((cP + 63) / 64, cL / 64, cB), blk, 0, stream>>>(
        convT, xpbw, ssmb, nullptr, nullptr,
        cL, cP, cDM, cDM, cDM, cP,
        (long)cL * cDM, 0L, (long)cL * cP, 0, 0);

    // 5. delta fwd: delta[b][d][l] = softplus(sum_r dtw[d][r]*ssm_f[b][l][r] + dtb[d])
    gemm_nt<<<dim3(cL / 64, cDM / 64, cB), blk, 0, stream>>>(
        dtw, ssmf, xbuf /*delta_f*/, nullptr, dtb,
        cDM, cL, cR, cR, cP, cL,
        0L, (long)cL * cP, (long)cDM * cL, 0, 1);

    // 6. delta bwd
    gemm_nt<<<dim3(cL / 64, cDM / 64, cB), blk, 0, stream>>>(
        dtbw, ssmb, deltab, nullptr, dtbb,
        cDM, cL, cR, cR, cP, cL,
        0L, (long)cL * cP, (long)cDM * cL, 0, 1);

    // 6.5 zero ysum (aliases convT) for atomic accumulation
    hipMemsetAsync(convT, 0, S * sizeof(float), stream);

    // 7. fused bidirectional scan (atomicAdd into ysum)
    scan2_kernel<<<dim3(cDM / 16, cB, 2), blk, 0, stream>>>(
        conv, gate, xbuf /*delta_f*/, deltab, ssmf, ssmb,
        Alog, Alogb, Dv, Dbv, convT /*ysum*/);

    // 8. out_proj: out[b][l][h] = sum_d ysum[b][l][d]*outw[h][d]
    gemm_nt<<<dim3(cH / 64, cL / 64, cB), blk, 0, stream>>>(
        convT, outw, out, nullptr, nullptr,
        cL, cH, cDM, cDM, cDM, cH,
        (long)cL * cDM, 0L, (long)cL * cH, 0, 0);
}

// Round 3
// 524.194 us; speedup vs baseline: 3.0077x; 1.2311x over previous
//
#include <hip/hip_runtime.h>
#include <math.h>

// Problem constants
constexpr int cH  = 768;
constexpr int cDM = 1536;
constexpr int cN  = 16;
constexpr int cR  = 48;
constexpr int cB  = 2;
constexpr int cL  = 1024;
constexpr int cP  = 80;   // R + 2N

typedef unsigned short u16;
typedef __attribute__((ext_vector_type(8))) short bf16x8;
typedef __attribute__((ext_vector_type(4))) float f32x4;

__device__ __forceinline__ u16 f2bf(float f) {
    unsigned u = __float_as_uint(f);
    u += 0x7FFF + ((u >> 16) & 1);          // RNE
    return (u16)(u >> 16);
}

// ---------------------------------------------------------------------------
// fp32 -> bf16 converts
// ---------------------------------------------------------------------------
__global__ __launch_bounds__(256)
void f2b_kernel(const float* __restrict__ in, u16* __restrict__ out, long n) {
    for (long i = (long)blockIdx.x * 256 + threadIdx.x; i < n; i += (long)gridDim.x * 256)
        out[i] = f2bf(in[i]);
}

// (rows x 48) fp32 -> (rows x 64) bf16, zero-padded
__global__ __launch_bounds__(256)
void padw_kernel(const float* __restrict__ in, u16* __restrict__ out, int rows) {
    int i = blockIdx.x * 256 + threadIdx.x;
    if (i >= rows * 64) return;
    int r = i >> 6, k = i & 63;
    out[i] = (k < cR) ? f2bf(in[r * cR + k]) : (u16)0;
}

// ssm (B,L,80) cols 0..47 -> (B,L,64) bf16, zero-padded
__global__ __launch_bounds__(256)
void tspad_kernel(const float* __restrict__ ssm, u16* __restrict__ out) {
    int i = blockIdx.x * 256 + threadIdx.x;   // exactly B*L*64 = 131072 threads
    int bl = i >> 6, k = i & 63;
    out[i] = (k < cR) ? f2bf(ssm[bl * cP + k]) : (u16)0;
}

// ---------------------------------------------------------------------------
// bf16 MFMA NT GEMM: C[m][n] = sum_k A[m][k]*B[n][k], fp32 out.
// 128x128 tile, 4 waves (2x2 of 64x64), BK=32, 16x16x32 MFMA.
// global_load_lds (16B) staging, XOR-swizzled LDS chunks (2-way max conflict).
// EPI: 0=store, 1=softplus(v+bias[m]), 2=atomicAdd (split-K).
// blockIdx.z = batch*kspl + ks. M multiple of 128 (grid.y), N2 arbitrary.
// ---------------------------------------------------------------------------
__device__ __forceinline__ void gld_lds16(const u16* g, u16* l) {
    __builtin_amdgcn_global_load_lds(
        (const __attribute__((address_space(1))) unsigned int*)g,
        (__attribute__((address_space(3))) unsigned int*)l, 16, 0, 0);
}

template<int EPI>
__global__ __launch_bounds__(256, 3)
void gemm_mfma(const u16* __restrict__ A, const u16* __restrict__ B,
               float* __restrict__ C0, float* __restrict__ C1,
               const float* __restrict__ bias,
               int N2, int Kd, int lda, int ldb, int ldc,
               long sA, long sB, long sC, int splitRow, int kspl)
{
    __shared__ __align__(16) u16 shA[4096];   // [128][32] bf16, chunk-swizzled
    __shared__ __align__(16) u16 shB[4096];
    const int tid  = threadIdx.x;
    const int wid  = tid >> 6, lane = tid & 63;
    const int lr   = lane & 15, lc = lane >> 4;
    const int z    = blockIdx.z;
    const int bz   = z / kspl, ks = z % kspl;
    const int kpc  = Kd / kspl;
    const int kbeg = ks * kpc, kend = kbeg + kpc;
    const int n0 = blockIdx.x * 128, m0 = blockIdx.y * 128;
    const u16* Ab = A + (long)bz * sA;
    const u16* Bb = B + (long)bz * sB;
    const int wm = (wid >> 1) * 64, wn = (wid & 1) * 64;

    f32x4 acc[4][4] = {};

    for (int k0 = kbeg; k0 < kend; k0 += 32) {
        __syncthreads();
        #pragma unroll
        for (int h = 0; h < 2; ++h) {
            const int q  = wid * 2 + h;            // 1KB stage unit
            const int rr = q * 16 + (lane >> 2);   // tile row this lane fills
            const int sw = (rr & 3) ^ ((rr >> 2) & 3);
            const int kg = k0 + (((lane & 3) ^ sw) << 3);  // inverse-swizzled src chunk
            gld_lds16(Ab + (long)(m0 + rr) * lda + kg, &shA[q * 512]);
            int nr = n0 + rr; if (nr > N2 - 1) nr = N2 - 1;   // clamp partial N tile
            gld_lds16(Bb + (long)nr * ldb + kg, &shB[q * 512]);
        }
        __syncthreads();
        bf16x8 af[4], bfr[4];
        #pragma unroll
        for (int i = 0; i < 4; ++i) {
            const int ra  = wm + i * 16 + lr;
            const int swa = (ra & 3) ^ ((ra >> 2) & 3);
            af[i] = *(const bf16x8*)&shA[ra * 32 + ((lc ^ swa) << 3)];
            const int rb  = wn + i * 16 + lr;
            const int swb = (rb & 3) ^ ((rb >> 2) & 3);
            bfr[i] = *(const bf16x8*)&shB[rb * 32 + ((lc ^ swb) << 3)];
        }
        #pragma unroll
        for (int i = 0; i < 4; ++i)
            #pragma unroll
            for (int j = 0; j < 4; ++j)
                acc[i][j] = __builtin_amdgcn_mfma_f32_16x16x32_bf16(af[i], bfr[j], acc[i][j], 0, 0, 0);
    }

    #pragma unroll
    for (int i = 0; i < 4; ++i) {
        #pragma unroll
        for (int e = 0; e < 4; ++e) {
            const int m = m0 + wm + i * 16 + lc * 4 + e;   // C/D row = (lane>>4)*4+reg
            float* crow;
            if (C1 != nullptr && m >= splitRow)
                crow = C1 + (long)bz * sC + (long)(m - splitRow) * ldc;
            else
                crow = C0 + (long)bz * sC + (long)m * ldc;
            const float bi = (EPI == 1) ? bias[m] : 0.f;
            #pragma unroll
            for (int j = 0; j < 4; ++j) {
                const int n = n0 + wn + j * 16 + lr;       // C/D col = lane&15
                if (n < N2) {
                    float v = acc[i][j][e];
                    if (EPI == 1) {
                        const float t = v + bi;
                        v = fmaxf(t, 0.f) + log1pf(__expf(-fabsf(t)));
                    }
                    if (EPI == 2) atomicAdd(crow + n, v);
                    else          crow[n] = v;
                }
            }
        }
    }
}

// ---------------------------------------------------------------------------
// Depthwise causal conv (K=4) + bias + SiLU. Writes fp32 (b,d,l) and bf16 (b,l,d).
// ---------------------------------------------------------------------------
__global__ __launch_bounds__(256)
void conv_silu_kernel(const float* __restrict__ x, const float* __restrict__ cw,
                      const float* __restrict__ cb,
                      float* __restrict__ conv, u16* __restrict__ convT)
{
    const int l = blockIdx.x * 256 + threadIdx.x;
    const int d = blockIdx.y;
    const int b = blockIdx.z;
    const float* xr = x + ((long)b * cDM + d) * cL;
    const float w0 = cw[d * 4 + 0], w1 = cw[d * 4 + 1];
    const float w2 = cw[d * 4 + 2], w3 = cw[d * 4 + 3];
    float v = cb[d] + w3 * xr[l];
    if (l >= 1) v = fmaf(w2, xr[l - 1], v);
    if (l >= 2) v = fmaf(w1, xr[l - 2], v);
    if (l >= 3) v = fmaf(w0, xr[l - 3], v);
    const float s = v / (1.f + __expf(-v));   // SiLU
    conv[((long)b * cDM + d) * cL + l] = s;
    convT[((long)b * cL + l) * cDM + d] = f2bf(s);
}

// ---------------------------------------------------------------------------
// Fused bidirectional selective scan, register-resident + software-pipelined.
// grid = (DM/16, B, 2); 16 lanes per channel (lane = state n).
// __launch_bounds__(256,4): 128-VGPR budget -> no scratch spill (round-2 bug).
// ---------------------------------------------------------------------------
#define LOADC(c, du, u, gv, Barr, Carr) do {                                  \
    const int l0_ = dir ? (cL - 1 - (c) * 16) : ((c) * 16);                   \
    const int ln_ = dir ? (l0_ - n) : (l0_ + n);                              \
    du = dp[ln_]; u = up[ln_]; gv = gp[ln_];                                  \
    _Pragma("unroll")                                                         \
    for (int t_ = 0; t_ < 16; ++t_) {                                         \
        const int lt_ = dir ? (l0_ - t_) : (l0_ + t_);                        \
        Barr[t_] = sp[lt_ * cP + cR + n];                                     \
        Carr[t_] = sp[lt_ * cP + cR + cN + n];                                \
    }                                                                         \
} while (0)

__global__ __launch_bounds__(256, 4)
void scan2_kernel(const float* __restrict__ conv,     // (B,DM,L)  u
                  const float* __restrict__ gate,     // (B,DM,L)
                  const float* __restrict__ delta_f,  // (B,DM,L)
                  const float* __restrict__ delta_b,
                  const float* __restrict__ ssm_f,    // (B,L,80)
                  const float* __restrict__ ssm_b,
                  const float* __restrict__ Alog_f,   // (DM,16)
                  const float* __restrict__ Alog_b,
                  const float* __restrict__ D_f,      // (DM)
                  const float* __restrict__ D_b,
                  float* __restrict__ ysum)           // (B,L,DM) zero-inited
{
    const int g = threadIdx.x >> 4;
    const int n = threadIdx.x & 15;
    const int d = blockIdx.x * 16 + g;
    const int b = blockIdx.y;
    const int dir = blockIdx.z;       // 0 = fwd, 1 = bwd

    const float* delta = dir ? delta_b : delta_f;
    const float* ssm   = dir ? ssm_b   : ssm_f;
    const float* Alog  = dir ? Alog_b  : Alog_f;
    const float  Dd    = dir ? D_b[d]  : D_f[d];
    const float  a     = -__expf(Alog[d * cN + n]);

    const float* up = conv  + ((long)b * cDM + d) * cL;
    const float* gp = gate  + ((long)b * cDM + d) * cL;
    const float* dp = delta + ((long)b * cDM + d) * cL;
    const float* sp = ssm + (long)b * cL * cP;

    float rB[16], rC[16];
    float du_n, u_n, gv_n;
    LOADC(0, du_n, u_n, gv_n, rB, rC);

    float xs = 0.f;
    for (int c = 0; c < cL / 16; ++c) {
        // precompute off the serial chain: dA[t], dBu[t] (in place in rB)
        float dA[16];
        #pragma unroll
        for (int t = 0; t < 16; ++t) {
            const float dut = __shfl(du_n, t, 16);
            const float ut  = __shfl(u_n,  t, 16);
            dA[t] = __expf(dut * a);
            rB[t] = (dut * ut) * rB[t];
        }
        // issue next chunk's loads so their latency hides under the chain
        float du2 = 0.f, u2 = 0.f, gv2 = 0.f, nB[16], nC[16];
        if (c < cL / 16 - 1) LOADC(c + 1, du2, u2, gv2, nB, nC);

        const int l0 = dir ? (cL - 1 - c * 16) : (c * 16);
        const int ln = dir ? (l0 - n) : (l0 + n);

        float yo = 0.f;
        #pragma unroll
        for (int t = 0; t < 16; ++t) {
            xs = fmaf(dA[t], xs, rB[t]);       // only serial dependence
            float y = xs * rC[t];
            y += __shfl_xor(y, 1);
            y += __shfl_xor(y, 2);
            y += __shfl_xor(y, 4);
            y += __shfl_xor(y, 8);
            if (n == t) yo = y;
        }

        const float val = (yo + u_n * Dd) * (gv_n / (1.f + __expf(-gv_n)));
        atomicAdd(&ysum[((long)b * cL + ln) * cDM + d], val);

        du_n = du2; u_n = u2; gv_n = gv2;
        #pragma unroll
        for (int t = 0; t < 16; ++t) { rB[t] = nB[t]; rC[t] = nC[t]; }
    }
}

// ---------------------------------------------------------------------------
extern "C" void kernel_launch(void* const* d_in, const int* in_sizes, int n_in,
                              void* d_out, int out_size, void* d_ws, size_t ws_size,
                              hipStream_t stream)
{
    const float* hid   = (const float*)d_in[0];   // (B,L,H)
    const float* inw   = (const float*)d_in[1];   // (2DM,H)
    const float* convw = (const float*)d_in[2];   // (DM,K)
    const float* convb = (const float*)d_in[3];   // (DM)
    const float* xpw   = (const float*)d_in[4];   // (80,DM)
    const float* dtw   = (const float*)d_in[5];   // (DM,R)
    const float* dtb   = (const float*)d_in[6];   // (DM)
    const float* xpbw  = (const float*)d_in[7];
    const float* dtbw  = (const float*)d_in[8];
    const float* dtbb  = (const float*)d_in[9];
    const float* Alog  = (const float*)d_in[10];  // (DM,16)
    const float* Alogb = (const float*)d_in[11];
    const float* Dv    = (const float*)d_in[12];
    const float* Dbv   = (const float*)d_in[13];
    const float* outw  = (const float*)d_in[14];  // (H,DM)
    float* out = (float*)d_out;                   // (B,L,H)

    float* ws = (float*)d_ws;
    const long S = (long)cB * cDM * cL;           // 3,145,728
    float* xbuf   = ws;                // x, then delta_f
    float* gate   = ws + S;
    float* conv   = ws + 2 * S;        // u fp32 (b,d,l)
    float* deltab = ws + 3 * S;
    float* ysum   = ws + 4 * S;        // fp32 (b,l,d)
    float* ssmf   = ws + 5 * S;        // (B,L,80) fp32
    float* ssmb   = ssmf + (long)cB * cL * cP;
    u16* convT_b  = (u16*)(ssmb + (long)cB * cL * cP);   // S bf16 elems
    float* poolA  = (float*)(convT_b + S);
    // phase 1 use of poolA:
    u16* inw_b = (u16*)poolA;                          // 2*DM*H   = 2,359,296
    u16* hid_b = inw_b + (long)2 * cDM * cH;           // B*L*H    = 1,572,864
    // phase 2 reuse (after in_proj done):
    u16* ysum_b = (u16*)poolA;                         // S elems
    u16* tsf_b  = ysum_b + S;                          // B*L*64
    u16* tsb_b  = tsf_b + (long)cB * cL * 64;
    // persistent weights after poolA (poolA = 3,932,160 u16 = 1,966,080 floats)
    u16* xpw_b  = (u16*)(poolA + 1966080);
    u16* xpbw_b = xpw_b  + (long)cP * cDM;
    u16* dtw_b  = xpbw_b + (long)cP * cDM;             // DM*64 padded
    u16* dtwb_b = dtw_b  + (long)cDM * 64;
    u16* outw_b = dtwb_b + (long)cDM * 64;             // H*DM

    const dim3 blk(256);

    // 0. dtype converts
    f2b_kernel<<<1024, blk, 0, stream>>>(hid,  hid_b,  (long)cB * cL * cH);
    f2b_kernel<<<1024, blk, 0, stream>>>(inw,  inw_b,  (long)2 * cDM * cH);
    f2b_kernel<<<480,  blk, 0, stream>>>(xpw,  xpw_b,  (long)cP * cDM);
    f2b_kernel<<<480,  blk, 0, stream>>>(xpbw, xpbw_b, (long)cP * cDM);
    f2b_kernel<<<1024, blk, 0, stream>>>(outw, outw_b, (long)cH * cDM);
    padw_kernel<<<384, blk, 0, stream>>>(dtw,  dtw_b,  cDM);
    padw_kernel<<<384, blk, 0, stream>>>(dtbw, dtwb_b, cDM);

    // 1. in_proj (M=3072 rows of W, N=L, K=H), split x / gate
    gemm_mfma<0><<<dim3(cL / 128, (2 * cDM) / 128, cB), blk, 0, stream>>>(
        inw_b, hid_b, xbuf, gate, nullptr,
        cL, cH, cH, cH, cL, 0L, (long)cL * cH, (long)cDM * cL, cDM, 1);

    // 2. causal conv + SiLU (fp32 u + bf16 transpose)
    conv_silu_kernel<<<dim3(cL / 256, cDM, cB), blk, 0, stream>>>(
        xbuf, convw, convb, conv, convT_b);

    // 3. zero ssm buffers (split-K atomic targets)
    hipMemsetAsync(ssmf, 0, (long)2 * cB * cL * cP * sizeof(float), stream);

    // 4-5. x_proj fwd/bwd: M=L, N=80, K=DM, split-K=4, atomicAdd
    gemm_mfma<2><<<dim3(1, cL / 128, cB * 4), blk, 0, stream>>>(
        convT_b, xpw_b, ssmf, nullptr, nullptr,
        cP, cDM, cDM, cDM, cP, (long)cL * cDM, 0L, (long)cL * cP, 1 << 30, 4);
    gemm_mfma<2><<<dim3(1, cL / 128, cB * 4), blk, 0, stream>>>(
        convT_b, xpbw_b, ssmb, nullptr, nullptr,
        cP, cDM, cDM, cDM, cP, (long)cL * cDM, 0L, (long)cL * cP, 1 << 30, 4);

    // 6. ts slices -> padded bf16
    tspad_kernel<<<512, blk, 0, stream>>>(ssmf, tsf_b);
    tspad_kernel<<<512, blk, 0, stream>>>(ssmb, tsb_b);

    // 7-8. delta fwd/bwd: M=DM, N=L, K=64(padded), softplus+bias epilogue
    gemm_mfma<1><<<dim3(cL / 128, cDM / 128, cB), blk, 0, stream>>>(
        dtw_b, tsf_b, xbuf /*delta_f*/, nullptr, dtb,
        cL, 64, 64, 64, cL, 0L, (long)cL * 64, (long)cDM * cL, 1 << 30, 1);
    gemm_mfma<1><<<dim3(cL / 128, cDM / 128, cB), blk, 0, stream>>>(
        dtwb_b, tsb_b, deltab, nullptr, dtbb,
        cL, 64, 64, 64, cL, 0L, (long)cL * 64, (long)cDM * cL, 1 << 30, 1);

    // 9. zero ysum, fused bidirectional scan
    hipMemsetAsync(ysum, 0, S * sizeof(float), stream);
    scan2_kernel<<<dim3(cDM / 16, cB, 2), blk, 0, stream>>>(
        conv, gate, xbuf /*delta_f*/, deltab, ssmf, ssmb,
        Alog, Alogb, Dv, Dbv, ysum);

    // 10. ysum -> bf16
    f2b_kernel<<<2048, blk, 0, stream>>>(ysum, ysum_b, S);

    // 11. out_proj: M=L, N=H, K=DM
    gemm_mfma<0><<<dim3(cH / 128, cL / 128, cB), blk, 0, stream>>>(
        ysum_b, outw_b, out, nullptr, nullptr,
        cH, cDM, cDM, cDM, cH, (long)cL * cDM, 0L, (long)cL * cH, 1 << 30, 1);
}

// Round 4
// 349.018 us; speedup vs baseline: 4.5174x; 1.5019x over previous
//
#include <hip/hip_runtime.h>
#include <math.h>

// Problem constants
constexpr int cH  = 768;
constexpr int cDM = 1536;
constexpr int cN  = 16;
constexpr int cR  = 48;
constexpr int cB  = 2;
constexpr int cL  = 1024;
constexpr int cPS = 160;  // stacked ssm row: [fwd 80 | bwd 80]

typedef unsigned short u16;
typedef __attribute__((ext_vector_type(8))) short bf16x8;
typedef __attribute__((ext_vector_type(4))) float f32x4;

__device__ __forceinline__ u16 f2bf(float f) {
    unsigned u = __float_as_uint(f);
    u += 0x7FFF + ((u >> 16) & 1);          // RNE
    return (u16)(u >> 16);
}
__device__ __forceinline__ float bf2f(u16 h) {
    return __uint_as_float((unsigned)h << 16);
}

// ---------------------------------------------------------------------------
// fp32 -> bf16 convert (grid-stride)
// ---------------------------------------------------------------------------
__global__ __launch_bounds__(256)
void f2b_kernel(const float* __restrict__ in, u16* __restrict__ out, long n) {
    for (long i = (long)blockIdx.x * 256 + threadIdx.x; i < n; i += (long)gridDim.x * 256)
        out[i] = f2bf(in[i]);
}

// (rows x 48) fp32 -> (rows x 64) bf16, zero-padded
__global__ __launch_bounds__(256)
void padw_kernel(const float* __restrict__ in, u16* __restrict__ out, int rows) {
    int i = blockIdx.x * 256 + threadIdx.x;
    if (i >= rows * 64) return;
    int r = i >> 6, k = i & 63;
    out[i] = (k < cR) ? f2bf(in[r * cR + k]) : (u16)0;
}

// ssms (B,L,160) ts-slices -> (2,B,L,64) bf16 zero-padded
__global__ __launch_bounds__(256)
void tspad_kernel(const float* __restrict__ ssms, u16* __restrict__ out) {
    int i = blockIdx.x * 256 + threadIdx.x;    // exactly 2*B*L*64 = 262144
    int dirsel = i >> 17;                       // / (B*L*64)
    int rem = i & 131071;
    int bl = rem >> 6, k = rem & 63;
    out[i] = (k < cR) ? f2bf(ssms[(long)bl * cPS + dirsel * 80 + k]) : (u16)0;
}

// yf (bf16) += yb (bf16), in place; feeds out_proj
__global__ __launch_bounds__(256)
void comb_kernel(u16* __restrict__ yf, const u16* __restrict__ yb, long n) {
    for (long i = (long)blockIdx.x * 256 + threadIdx.x; i < n; i += (long)gridDim.x * 256)
        yf[i] = f2bf(bf2f(yf[i]) + bf2f(yb[i]));
}

// ---------------------------------------------------------------------------
// bf16 MFMA NT GEMM: C[m][n] = sum_k A[m][k]*B[n][k], fp32 out.
// 128x128 tile, 4 waves, BK=32, 16x16x32 MFMA, global_load_lds staging,
// XOR-swizzled LDS chunks. EPI: 0=store, 1=softplus(v+bias), 2=atomicAdd.
// B_hi/bias_hi: if non-null and m0>=splitRow, use them (fused fwd/bwd delta).
// C1/splitRow: row-split output (in_proj x|gate, delta f|b).
// blockIdx.z = batch*kspl + ks (split-K, EPI=2 target must be zeroed).
// ---------------------------------------------------------------------------
__device__ __forceinline__ void gld_lds16(const u16* g, u16* l) {
    __builtin_amdgcn_global_load_lds(
        (const __attribute__((address_space(1))) unsigned int*)g,
        (__attribute__((address_space(3))) unsigned int*)l, 16, 0, 0);
}

template<int EPI>
__global__ __launch_bounds__(256, 3)
void gemm_mfma(const u16* __restrict__ A, const u16* __restrict__ B,
               const u16* __restrict__ B_hi,
               float* __restrict__ C0, float* __restrict__ C1,
               const float* __restrict__ bias, const float* __restrict__ bias_hi,
               int N2, int Kd, int lda, int ldb, int ldc,
               long sA, long sB, long sC, int splitRow, int kspl)
{
    __shared__ __align__(16) u16 shA[4096];   // [128][32] bf16, chunk-swizzled
    __shared__ __align__(16) u16 shB[4096];
    const int tid  = threadIdx.x;
    const int wid  = tid >> 6, lane = tid & 63;
    const int lr   = lane & 15, lc = lane >> 4;
    const int z    = blockIdx.z;
    const int bz   = z / kspl, ks = z % kspl;
    const int kpc  = Kd / kspl;
    const int kbeg = ks * kpc, kend = kbeg + kpc;
    const int n0 = blockIdx.x * 128, m0 = blockIdx.y * 128;

    const u16* Bsel = (B_hi != nullptr && m0 >= splitRow) ? B_hi : B;
    const float* biasp = (bias_hi != nullptr && m0 >= splitRow) ? bias_hi : bias;
    const int mro = (bias_hi != nullptr && m0 >= splitRow) ? splitRow : 0;

    const u16* Ab = A + (long)bz * sA;
    const u16* Bb = Bsel + (long)bz * sB;
    const int wm = (wid >> 1) * 64, wn = (wid & 1) * 64;

    f32x4 acc[4][4] = {};

    for (int k0 = kbeg; k0 < kend; k0 += 32) {
        __syncthreads();
        #pragma unroll
        for (int h = 0; h < 2; ++h) {
            const int q  = wid * 2 + h;            // 1KB stage unit
            const int rr = q * 16 + (lane >> 2);   // tile row this lane fills
            const int sw = (rr & 3) ^ ((rr >> 2) & 3);
            const int kg = k0 + (((lane & 3) ^ sw) << 3);  // inverse-swizzled src
            gld_lds16(Ab + (long)(m0 + rr) * lda + kg, &shA[q * 512]);
            int nr = n0 + rr; if (nr > N2 - 1) nr = N2 - 1;   // clamp partial N
            gld_lds16(Bb + (long)nr * ldb + kg, &shB[q * 512]);
        }
        __syncthreads();
        bf16x8 af[4], bfr[4];
        #pragma unroll
        for (int i = 0; i < 4; ++i) {
            const int ra  = wm + i * 16 + lr;
            const int swa = (ra & 3) ^ ((ra >> 2) & 3);
            af[i] = *(const bf16x8*)&shA[ra * 32 + ((lc ^ swa) << 3)];
            const int rb  = wn + i * 16 + lr;
            const int swb = (rb & 3) ^ ((rb >> 2) & 3);
            bfr[i] = *(const bf16x8*)&shB[rb * 32 + ((lc ^ swb) << 3)];
        }
        #pragma unroll
        for (int i = 0; i < 4; ++i)
            #pragma unroll
            for (int j = 0; j < 4; ++j)
                acc[i][j] = __builtin_amdgcn_mfma_f32_16x16x32_bf16(af[i], bfr[j], acc[i][j], 0, 0, 0);
    }

    #pragma unroll
    for (int i = 0; i < 4; ++i) {
        #pragma unroll
        for (int e = 0; e < 4; ++e) {
            const int m = m0 + wm + i * 16 + lc * 4 + e;   // C/D row
            float* crow;
            if (C1 != nullptr && m >= splitRow)
                crow = C1 + (long)bz * sC + (long)(m - splitRow) * ldc;
            else
                crow = C0 + (long)bz * sC + (long)m * ldc;
            const float bi = (EPI == 1) ? biasp[m - mro] : 0.f;
            #pragma unroll
            for (int j = 0; j < 4; ++j) {
                const int n = n0 + wn + j * 16 + lr;       // C/D col
                if (n < N2) {
                    float v = acc[i][j][e];
                    if (EPI == 1) {
                        const float t = v + bi;
                        v = fmaxf(t, 0.f) + log1pf(__expf(-fabsf(t)));
                    }
                    if (EPI == 2) atomicAdd(crow + n, v);
                    else          crow[n] = v;
                }
            }
        }
    }
}

// ---------------------------------------------------------------------------
// Depthwise causal conv (K=4) + bias + SiLU, 32x32 LDS tiles.
// Reads x (b,d,l) coalesced; writes conv fp32 (b,d,l) and convT bf16 (b,l,d),
// both coalesced (old version scattered 2B stores at stride 3KB).
// ---------------------------------------------------------------------------
__global__ __launch_bounds__(256)
void conv_silu_t(const float* __restrict__ x, const float* __restrict__ cw,
                 const float* __restrict__ cb,
                 float* __restrict__ conv, u16* __restrict__ convT)
{
    __shared__ float xs_[32][36];   // [d][l0-3 .. l0+31]
    __shared__ float cs[32][33];    // [l][d]
    const int l0 = blockIdx.x * 32, d0 = blockIdx.y * 32, b = blockIdx.z;
    const int lx = threadIdx.x & 31, dy = threadIdx.x >> 5;

    #pragma unroll
    for (int r = 0; r < 4; ++r) {
        const int dd = dy + r * 8;
        const float* xr = x + ((long)b * cDM + d0 + dd) * cL;
        const int li = l0 - 3 + lx;
        xs_[dd][lx] = (li >= 0) ? xr[li] : 0.f;
        if (lx < 3) xs_[dd][32 + lx] = xr[l0 + 29 + lx];
    }
    __syncthreads();
    #pragma unroll
    for (int r = 0; r < 4; ++r) {
        const int dd = dy + r * 8;
        const int d = d0 + dd;
        const float w0 = cw[d*4], w1 = cw[d*4+1], w2 = cw[d*4+2], w3 = cw[d*4+3];
        float v = cb[d];
        v = fmaf(w0, xs_[dd][lx],     v);
        v = fmaf(w1, xs_[dd][lx + 1], v);
        v = fmaf(w2, xs_[dd][lx + 2], v);
        v = fmaf(w3, xs_[dd][lx + 3], v);
        const float s = v / (1.f + __expf(-v));   // SiLU
        conv[((long)b * cDM + d) * cL + l0 + lx] = s;
        cs[lx][dd] = s;
    }
    __syncthreads();
    #pragma unroll
    for (int r = 0; r < 4; ++r) {
        const int ll = dy + r * 8;
        convT[((long)b * cL + l0 + ll) * cDM + d0 + lx] = f2bf(cs[ll][lx]);
    }
}

// ---------------------------------------------------------------------------
// Fused bidirectional selective scan, spill-free (live set ~50 VGPR).
// grid = (DM/16, B, 2); 16 lanes per channel (lane = state n); chunk = 8.
// Each dir writes its own bf16 buffer (plain stores, no atomics/memset).
// ---------------------------------------------------------------------------
__global__ __launch_bounds__(256, 4)
void scan2_kernel(const float* __restrict__ conv,     // (B,DM,L)  u
                  const float* __restrict__ gate,     // (B,DM,L)
                  const float* __restrict__ delta_f,  // (B,DM,L)
                  const float* __restrict__ delta_b,
                  const float* __restrict__ ssms,     // (B,L,160)
                  const float* __restrict__ Alog_f,   // (DM,16)
                  const float* __restrict__ Alog_b,
                  const float* __restrict__ D_f,      // (DM)
                  const float* __restrict__ D_b,
                  u16* __restrict__ yf,               // (B,L,DM) bf16
                  u16* __restrict__ yb)
{
    const int g = threadIdx.x >> 4;
    const int n = threadIdx.x & 15;
    const int d = blockIdx.x * 16 + g;
    const int b = blockIdx.y;
    const int dir = blockIdx.z;       // 0 = fwd, 1 = bwd

    const float* delta = dir ? delta_b : delta_f;
    const float* Alog  = dir ? Alog_b  : Alog_f;
    const float  Dd    = dir ? D_b[d]  : D_f[d];
    u16*         yout  = dir ? yb      : yf;
    const float  a     = -__expf(Alog[d * cN + n]);
    const int    sofs  = dir ? 128 : 48;   // B col base; C at +16

    const float* up = conv  + ((long)b * cDM + d) * cL;
    const float* gp = gate  + ((long)b * cDM + d) * cL;
    const float* dp = delta + ((long)b * cDM + d) * cL;
    const float* sp = ssms + (long)b * cL * cPS;

    float xs = 0.f;
    for (int c = 0; c < cL / 8; ++c) {
        const int l0 = dir ? (cL - 1 - c * 8) : (c * 8);
        const int t8 = n & 7;
        const int lt = dir ? (l0 - t8) : (l0 + t8);   // own slot (dup x2)
        const float du_n = dp[lt];
        const float u_n  = up[lt];

        float B8[8], C8[8];
        #pragma unroll
        for (int t = 0; t < 8; ++t) {
            const int l = dir ? (l0 - t) : (l0 + t);
            B8[t] = sp[(long)l * cPS + sofs + n];
            C8[t] = sp[(long)l * cPS + sofs + 16 + n];
        }
        float dA[8];
        #pragma unroll
        for (int t = 0; t < 8; ++t) {
            const float dut = __shfl(du_n, t, 16);
            const float ut  = __shfl(u_n,  t, 16);
            dA[t] = __expf(dut * a);
            B8[t] = (dut * ut) * B8[t];
        }
        float yo = 0.f;
        #pragma unroll
        for (int t = 0; t < 8; ++t) {
            xs = fmaf(dA[t], xs, B8[t]);      // only serial dependence
            float y = xs * C8[t];
            y += __shfl_xor(y, 1);
            y += __shfl_xor(y, 2);
            y += __shfl_xor(y, 4);
            y += __shfl_xor(y, 8);
            if (n == t) yo = y;               // lanes 0..7 capture
        }
        if (n < 8) {
            const float gv = gp[lt];
            const float val = (yo + u_n * Dd) * (gv / (1.f + __expf(-gv)));
            yout[((long)b * cL + lt) * cDM + d] = f2bf(val);
        }
    }
}

// ---------------------------------------------------------------------------
extern "C" void kernel_launch(void* const* d_in, const int* in_sizes, int n_in,
                              void* d_out, int out_size, void* d_ws, size_t ws_size,
                              hipStream_t stream)
{
    const float* hid   = (const float*)d_in[0];   // (B,L,H)
    const float* inw   = (const float*)d_in[1];   // (2DM,H)
    const float* convw = (const float*)d_in[2];   // (DM,K)
    const float* convb = (const float*)d_in[3];   // (DM)
    const float* xpw   = (const float*)d_in[4];   // (80,DM)
    const float* dtw   = (const float*)d_in[5];   // (DM,R)
    const float* dtb   = (const float*)d_in[6];   // (DM)
    const float* xpbw  = (const float*)d_in[7];
    const float* dtbw  = (const float*)d_in[8];
    const float* dtbb  = (const float*)d_in[9];
    const float* Alog  = (const float*)d_in[10];  // (DM,16)
    const float* Alogb = (const float*)d_in[11];
    const float* Dv    = (const float*)d_in[12];
    const float* Dbv   = (const float*)d_in[13];
    const float* outw  = (const float*)d_in[14];  // (H,DM)
    float* out = (float*)d_out;                   // (B,L,H)

    float* ws = (float*)d_ws;
    const long S = (long)cB * cDM * cL;           // 3,145,728
    float* xbuf   = ws;                // x, then delta_f
    float* gate   = ws + S;
    float* conv   = ws + 2 * S;        // u fp32 (b,d,l)
    float* deltab = ws + 3 * S;
    float* ssms   = ws + 4 * S;        // (B,L,160) fp32
    u16* up0      = (u16*)(ssms + (long)cB * cL * cPS);
    u16* convT_b  = up0;                              // S u16; later yf/ysum
    u16* ts2_b    = up0 + S;                          // 2*B*L*64 = 262,144
    u16* xpw2_b   = ts2_b + (long)2 * cB * cL * 64;   // 160*DM stacked
    u16* dtw2_b   = xpw2_b + (long)cPS * cDM;         // 2*DM*64 stacked
    u16* outw_b   = dtw2_b + (long)2 * cDM * 64;      // H*DM
    u16* pool2    = outw_b + (long)cH * cDM;          // 3,932,160 u16
    u16* inw_b    = pool2;                            // 2*DM*H (phase 1)
    u16* hid_b    = pool2 + (long)2 * cDM * cH;       // B*L*H  (phase 1)
    u16* yf_b     = convT_b;                          // phase 2 (after x_proj)
    u16* yb_b     = pool2;                            // phase 2 (after in_proj)

    const dim3 blk(256);

    // 0. dtype converts (weights stacked for fused GEMMs)
    f2b_kernel<<<1024, blk, 0, stream>>>(hid,  hid_b,  (long)cB * cL * cH);
    f2b_kernel<<<1024, blk, 0, stream>>>(inw,  inw_b,  (long)2 * cDM * cH);
    f2b_kernel<<<480,  blk, 0, stream>>>(xpw,  xpw2_b, (long)80 * cDM);
    f2b_kernel<<<480,  blk, 0, stream>>>(xpbw, xpw2_b + (long)80 * cDM, (long)80 * cDM);
    f2b_kernel<<<1024, blk, 0, stream>>>(outw, outw_b, (long)cH * cDM);
    padw_kernel<<<384, blk, 0, stream>>>(dtw,  dtw2_b,  cDM);
    padw_kernel<<<384, blk, 0, stream>>>(dtbw, dtw2_b + (long)cDM * 64, cDM);

    // split-K atomic targets must be zeroed
    hipMemsetAsync(ssms, 0, (long)cB * cL * cPS * sizeof(float), stream);
    hipMemsetAsync(out, 0, (long)out_size * sizeof(float), stream);

    // 1. in_proj (M=3072, N=L, K=H), split x | gate
    gemm_mfma<0><<<dim3(cL / 128, (2 * cDM) / 128, cB), blk, 0, stream>>>(
        inw_b, hid_b, nullptr, xbuf, gate, nullptr, nullptr,
        cL, cH, cH, cH, cL, 0L, (long)cL * cH, (long)cDM * cL, cDM, 1);

    // 2. causal conv + SiLU (tiled; both outputs coalesced)
    conv_silu_t<<<dim3(cL / 32, cDM / 32, cB), blk, 0, stream>>>(
        xbuf, convw, convb, conv, convT_b);

    // 3. fused x_proj fwd+bwd: M=L, N=160, K=DM, split-K=8
    gemm_mfma<2><<<dim3(2, cL / 128, cB * 8), blk, 0, stream>>>(
        convT_b, xpw2_b, nullptr, ssms, nullptr, nullptr, nullptr,
        cPS, cDM, cDM, cDM, cPS, (long)cL * cDM, 0L, (long)cL * cPS, 1 << 30, 8);

    // 4. ts slices -> padded bf16 (2,B,L,64)
    tspad_kernel<<<1024, blk, 0, stream>>>(ssms, ts2_b);

    // 5. fused delta fwd+bwd: M=3072, N=L, K=64; B/bias switch at m=1536
    gemm_mfma<1><<<dim3(cL / 128, (2 * cDM) / 128, cB), blk, 0, stream>>>(
        dtw2_b, ts2_b, ts2_b + (long)cB * cL * 64,
        xbuf /*delta_f*/, deltab, dtb, dtbb,
        cL, 64, 64, 64, cL, 0L, (long)cL * 64, (long)cDM * cL, cDM, 1);

    // 6. fused bidirectional scan (plain bf16 stores per dir)
    scan2_kernel<<<dim3(cDM / 16, cB, 2), blk, 0, stream>>>(
        conv, gate, xbuf /*delta_f*/, deltab, ssms,
        Alog, Alogb, Dv, Dbv, yf_b, yb_b);

    // 7. combine: yf += yb (in place, bf16)
    comb_kernel<<<2048, blk, 0, stream>>>(yf_b, yb_b, S);

    // 8. out_proj: M=L, N=H, K=DM, split-K=2 (out zeroed above)
    gemm_mfma<2><<<dim3(cH / 128, cL / 128, cB * 2), blk, 0, stream>>>(
        yf_b, outw_b, nullptr, out, nullptr, nullptr, nullptr,
        cH, cDM, cDM, cDM, cH, (long)cL * cDM, 0L, (long)cL * cH, 1 << 30, 2);
}

// Round 5
// 322.004 us; speedup vs baseline: 4.8963x; 1.0839x over previous
//
#include <hip/hip_runtime.h>
#include <math.h>

// Problem constants
constexpr int cH  = 768;
constexpr int cDM = 1536;
constexpr int cN  = 16;
constexpr int cR  = 48;
constexpr int cB  = 2;
constexpr int cL  = 1024;
constexpr int cPS = 160;  // stacked ssm row: [fwd 80 | bwd 80]

typedef unsigned short u16;
typedef __attribute__((ext_vector_type(8))) short bf16x8;
typedef __attribute__((ext_vector_type(4))) float f32x4;

__device__ __forceinline__ u16 f2bf(float f) {
    unsigned u = __float_as_uint(f);
    u += 0x7FFF + ((u >> 16) & 1);          // RNE
    return (u16)(u >> 16);
}
__device__ __forceinline__ float bf2f(u16 h) {
    return __uint_as_float((unsigned)h << 16);
}

// ---------------------------------------------------------------------------
// fp32 -> bf16 convert (grid-stride)
// ---------------------------------------------------------------------------
__global__ __launch_bounds__(256)
void f2b_kernel(const float* __restrict__ in, u16* __restrict__ out, long n) {
    for (long i = (long)blockIdx.x * 256 + threadIdx.x; i < n; i += (long)gridDim.x * 256)
        out[i] = f2bf(in[i]);
}

// (rows x 48) fp32 -> (rows x 64) bf16, zero-padded
__global__ __launch_bounds__(256)
void padw_kernel(const float* __restrict__ in, u16* __restrict__ out, int rows) {
    int i = blockIdx.x * 256 + threadIdx.x;
    if (i >= rows * 64) return;
    int r = i >> 6, k = i & 63;
    out[i] = (k < cR) ? f2bf(in[r * cR + k]) : (u16)0;
}

// ssms (B,L,160) ts-slices -> (2,B,L,64) bf16 zero-padded
__global__ __launch_bounds__(256)
void tspad_kernel(const float* __restrict__ ssms, u16* __restrict__ out) {
    int i = blockIdx.x * 256 + threadIdx.x;    // exactly 2*B*L*64 = 262144
    int dirsel = i >> 17;
    int rem = i & 131071;
    int bl = rem >> 6, k = rem & 63;
    out[i] = (k < cR) ? f2bf(ssms[(long)bl * cPS + dirsel * 80 + k]) : (u16)0;
}

// yf (bf16) += yb (bf16), in place, 8 elems/thread
__global__ __launch_bounds__(256)
void comb_kernel(u16* __restrict__ yf, const u16* __restrict__ yb, long n8) {
    long i = (long)blockIdx.x * 256 + threadIdx.x;
    if (i >= n8) return;
    uint4 av = ((uint4*)yf)[i];
    uint4 bv = ((const uint4*)yb)[i];
    unsigned* ap = (unsigned*)&av;
    unsigned* bp = (unsigned*)&bv;
    #pragma unroll
    for (int j = 0; j < 4; ++j) {
        const float lo = bf2f((u16)(ap[j] & 0xffff)) + bf2f((u16)(bp[j] & 0xffff));
        const float hi = bf2f((u16)(ap[j] >> 16))    + bf2f((u16)(bp[j] >> 16));
        ap[j] = (unsigned)f2bf(lo) | ((unsigned)f2bf(hi) << 16);
    }
    ((uint4*)yf)[i] = av;
}

// ---------------------------------------------------------------------------
// bf16 MFMA NT GEMM: C[m][n] = sum_k A[m][k]*B[n][k], fp32 out.
// 128x128 tile, 4 waves, BK=32, 16x16x32 MFMA, global_load_lds staging,
// XOR-swizzled LDS chunks. EPI: 0=store, 1=softplus(v+bias), 2=atomicAdd.
// B_hi/bias_hi: if non-null and m0>=splitRow, use them (fused fwd/bwd delta).
// C1/splitRow: row-split output. blockIdx.z = batch*kspl + ks (split-K).
// ---------------------------------------------------------------------------
__device__ __forceinline__ void gld_lds16(const u16* g, u16* l) {
    __builtin_amdgcn_global_load_lds(
        (const __attribute__((address_space(1))) unsigned int*)g,
        (__attribute__((address_space(3))) unsigned int*)l, 16, 0, 0);
}

template<int EPI>
__global__ __launch_bounds__(256, 3)
void gemm_mfma(const u16* __restrict__ A, const u16* __restrict__ B,
               const u16* __restrict__ B_hi,
               float* __restrict__ C0, float* __restrict__ C1,
               const float* __restrict__ bias, const float* __restrict__ bias_hi,
               int N2, int Kd, int lda, int ldb, int ldc,
               long sA, long sB, long sC, int splitRow, int kspl)
{
    __shared__ __align__(16) u16 shA[4096];   // [128][32] bf16, chunk-swizzled
    __shared__ __align__(16) u16 shB[4096];
    const int tid  = threadIdx.x;
    const int wid  = tid >> 6, lane = tid & 63;
    const int lr   = lane & 15, lc = lane >> 4;
    const int z    = blockIdx.z;
    const int bz   = z / kspl, ks = z % kspl;
    const int kpc  = Kd / kspl;
    const int kbeg = ks * kpc, kend = kbeg + kpc;
    const int n0 = blockIdx.x * 128, m0 = blockIdx.y * 128;

    const u16* Bsel = (B_hi != nullptr && m0 >= splitRow) ? B_hi : B;
    const float* biasp = (bias_hi != nullptr && m0 >= splitRow) ? bias_hi : bias;
    const int mro = (bias_hi != nullptr && m0 >= splitRow) ? splitRow : 0;

    const u16* Ab = A + (long)bz * sA;
    const u16* Bb = Bsel + (long)bz * sB;
    const int wm = (wid >> 1) * 64, wn = (wid & 1) * 64;

    f32x4 acc[4][4] = {};

    for (int k0 = kbeg; k0 < kend; k0 += 32) {
        __syncthreads();
        #pragma unroll
        for (int h = 0; h < 2; ++h) {
            const int q  = wid * 2 + h;            // 1KB stage unit
            const int rr = q * 16 + (lane >> 2);   // tile row this lane fills
            const int sw = (rr & 3) ^ ((rr >> 2) & 3);
            const int kg = k0 + (((lane & 3) ^ sw) << 3);  // inverse-swizzled src
            gld_lds16(Ab + (long)(m0 + rr) * lda + kg, &shA[q * 512]);
            int nr = n0 + rr; if (nr > N2 - 1) nr = N2 - 1;   // clamp partial N
            gld_lds16(Bb + (long)nr * ldb + kg, &shB[q * 512]);
        }
        __syncthreads();
        bf16x8 af[4], bfr[4];
        #pragma unroll
        for (int i = 0; i < 4; ++i) {
            const int ra  = wm + i * 16 + lr;
            const int swa = (ra & 3) ^ ((ra >> 2) & 3);
            af[i] = *(const bf16x8*)&shA[ra * 32 + ((lc ^ swa) << 3)];
            const int rb  = wn + i * 16 + lr;
            const int swb = (rb & 3) ^ ((rb >> 2) & 3);
            bfr[i] = *(const bf16x8*)&shB[rb * 32 + ((lc ^ swb) << 3)];
        }
        #pragma unroll
        for (int i = 0; i < 4; ++i)
            #pragma unroll
            for (int j = 0; j < 4; ++j)
                acc[i][j] = __builtin_amdgcn_mfma_f32_16x16x32_bf16(af[i], bfr[j], acc[i][j], 0, 0, 0);
    }

    #pragma unroll
    for (int i = 0; i < 4; ++i) {
        #pragma unroll
        for (int e = 0; e < 4; ++e) {
            const int m = m0 + wm + i * 16 + lc * 4 + e;   // C/D row
            float* crow;
            if (C1 != nullptr && m >= splitRow)
                crow = C1 + (long)bz * sC + (long)(m - splitRow) * ldc;
            else
                crow = C0 + (long)bz * sC + (long)m * ldc;
            const float bi = (EPI == 1) ? biasp[m - mro] : 0.f;
            #pragma unroll
            for (int j = 0; j < 4; ++j) {
                const int n = n0 + wn + j * 16 + lr;       // C/D col
                if (n < N2) {
                    float v = acc[i][j][e];
                    if (EPI == 1) {
                        const float t = v + bi;
                        v = fmaxf(t, 0.f) + log1pf(__expf(-fabsf(t)));
                    }
                    if (EPI == 2) atomicAdd(crow + n, v);
                    else          crow[n] = v;
                }
            }
        }
    }
}

// ---------------------------------------------------------------------------
// Depthwise causal conv (K=4) + bias + SiLU, 32x32 LDS tiles.
// ---------------------------------------------------------------------------
__global__ __launch_bounds__(256)
void conv_silu_t(const float* __restrict__ x, const float* __restrict__ cw,
                 const float* __restrict__ cb,
                 float* __restrict__ conv, u16* __restrict__ convT)
{
    __shared__ float xs_[32][36];   // [d][l0-3 .. l0+31]
    __shared__ float cs[32][33];    // [l][d]
    const int l0 = blockIdx.x * 32, d0 = blockIdx.y * 32, b = blockIdx.z;
    const int lx = threadIdx.x & 31, dy = threadIdx.x >> 5;

    #pragma unroll
    for (int r = 0; r < 4; ++r) {
        const int dd = dy + r * 8;
        const float* xr = x + ((long)b * cDM + d0 + dd) * cL;
        const int li = l0 - 3 + lx;
        xs_[dd][lx] = (li >= 0) ? xr[li] : 0.f;
        if (lx < 3) xs_[dd][32 + lx] = xr[l0 + 29 + lx];
    }
    __syncthreads();
    #pragma unroll
    for (int r = 0; r < 4; ++r) {
        const int dd = dy + r * 8;
        const int d = d0 + dd;
        const float w0 = cw[d*4], w1 = cw[d*4+1], w2 = cw[d*4+2], w3 = cw[d*4+3];
        float v = cb[d];
        v = fmaf(w0, xs_[dd][lx],     v);
        v = fmaf(w1, xs_[dd][lx + 1], v);
        v = fmaf(w2, xs_[dd][lx + 2], v);
        v = fmaf(w3, xs_[dd][lx + 3], v);
        const float s = v / (1.f + __expf(-v));   // SiLU
        conv[((long)b * cDM + d) * cL + l0 + lx] = s;
        cs[lx][dd] = s;
    }
    __syncthreads();
    #pragma unroll
    for (int r = 0; r < 4; ++r) {
        const int ll = dy + r * 8;
        convT[((long)b * cL + l0 + ll) * cDM + d0 + lx] = f2bf(cs[ll][lx]);
    }
}

// ---------------------------------------------------------------------------
// Fused bidirectional selective scan, LDS-staged 64-step windows,
// double-buffered (global loads for window w+1 overlap compute of w).
// grid = (DM/16, B, 2); block = 256 = 16 channels x 16 lanes (lane = state n).
// B/C staged ONCE per block (was 16x redundant); u/delta/gate staged
// per-channel via coalesced float4. Serial path touches only LDS.
// ---------------------------------------------------------------------------
#define STAGE_LOAD(w) do {                                                    \
    const int wt_ = (w) * 64 + t_bc;                                          \
    const int lb_ = dir ? (cL - 1 - wt_) : wt_;                               \
    rbc0 = *(const float4*)&sp[(long)lb_ * cPS + sofs + c0];                  \
    rbc1 = *(const float4*)&sp[(long)lb_ * cPS + sofs + c0 + 4];              \
    const int ut_ = (w) * 64 + t0_u;                                          \
    if (!dir) {                                                               \
        ru = *(const float4*)&up[ut_];                                        \
        rd = *(const float4*)&dp[ut_];                                        \
        rg = *(const float4*)&gp[ut_];                                        \
    } else {                                                                  \
        const int lo_ = cL - 4 - ut_;                                         \
        ru = *(const float4*)&up[lo_];                                        \
        rd = *(const float4*)&dp[lo_];                                        \
        rg = *(const float4*)&gp[lo_];                                        \
    }                                                                         \
} while (0)

#define STAGE_WRITE(bufi) do {                                                \
    *(float4*)&bcS[bufi][t_bc][c0]     = rbc0;                                \
    *(float4*)&bcS[bufi][t_bc][c0 + 4] = rbc1;                                \
    if (!dir) {                                                               \
        *(float4*)&uS[bufi][g][t0_u] = ru;                                    \
        *(float4*)&dS[bufi][g][t0_u] = rd;                                    \
        *(float4*)&gS[bufi][g][t0_u] = rg;                                    \
    } else {                                                                  \
        *(float4*)&uS[bufi][g][t0_u] = make_float4(ru.w, ru.z, ru.y, ru.x);   \
        *(float4*)&dS[bufi][g][t0_u] = make_float4(rd.w, rd.z, rd.y, rd.x);   \
        *(float4*)&gS[bufi][g][t0_u] = make_float4(rg.w, rg.z, rg.y, rg.x);   \
    }                                                                         \
} while (0)

__global__ __launch_bounds__(256, 2)
void scan3_kernel(const float* __restrict__ conv,     // (B,DM,L)  u
                  const float* __restrict__ gate,     // (B,DM,L)
                  const float* __restrict__ delta_f,  // (B,DM,L)
                  const float* __restrict__ delta_b,
                  const float* __restrict__ ssms,     // (B,L,160)
                  const float* __restrict__ Alog_f,   // (DM,16)
                  const float* __restrict__ Alog_b,
                  const float* __restrict__ D_f,      // (DM)
                  const float* __restrict__ D_b,
                  u16* __restrict__ yf,               // (B,L,DM) bf16
                  u16* __restrict__ yb)
{
    __shared__ float bcS[2][64][32];   // [buf][t][c]: c<16 -> B_n, c>=16 -> C_n
    __shared__ float uS[2][16][68];    // [buf][ch][t], stride-68: conflict-free
    __shared__ float dS[2][16][68];
    __shared__ float gS[2][16][68];

    const int tid = threadIdx.x;
    const int g = tid >> 4, n = tid & 15;
    const int d = blockIdx.x * 16 + g;
    const int b = blockIdx.y;
    const int dir = blockIdx.z;       // 0 = fwd, 1 = bwd

    const float* delta = dir ? delta_b : delta_f;
    const float* Alog  = dir ? Alog_b  : Alog_f;
    const float  Dd    = dir ? D_b[d]  : D_f[d];
    u16*         yout  = dir ? yb      : yf;
    const float  a     = -__expf(Alog[d * cN + n]);
    const int    sofs  = dir ? 128 : 48;

    // staging index maps
    const int t_bc = tid >> 2;          // 0..63: bc row staged by this thread
    const int c0   = (tid & 3) << 3;    // 0,8,16,24: 8 contiguous cols
    const int t0_u = n << 2;            // 0..60: 4 steps of channel g

    const float* up = conv  + ((long)b * cDM + d) * cL;   // channel g's row
    const float* gp = gate  + ((long)b * cDM + d) * cL;
    const float* dp = delta + ((long)b * cDM + d) * cL;
    const float* sp = ssms + (long)b * cL * cPS;

    float4 rbc0, rbc1, ru, rd, rg;
    STAGE_LOAD(0);
    STAGE_WRITE(0);
    __syncthreads();

    float xs = 0.f;
    for (int w = 0; w < cL / 64; ++w) {
        const int cur = w & 1;
        if (w < cL / 64 - 1) STAGE_LOAD(w + 1);   // overlaps compute below

        for (int s = 0; s < 8; ++s) {
            float dA8[8], dBu8[8], C8[8];
            #pragma unroll
            for (int k = 0; k < 8; ++k) {
                const int t = s * 8 + k;
                const float du = dS[cur][g][t];    // LDS broadcast across n
                const float uu = uS[cur][g][t];
                dA8[k]  = __expf(du * a);
                dBu8[k] = (du * uu) * bcS[cur][t][n];
                C8[k]   = bcS[cur][t][16 + n];
            }
            float yo = 0.f;
            #pragma unroll
            for (int k = 0; k < 8; ++k) {
                xs = fmaf(dA8[k], xs, dBu8[k]);    // only serial dependence
                float y = xs * C8[k];
                y += __shfl_xor(y, 1);
                y += __shfl_xor(y, 2);
                y += __shfl_xor(y, 4);
                y += __shfl_xor(y, 8);
                if (n == k) yo = y;
            }
            if (n < 8) {
                const int t = s * 8 + n;
                const float uu = uS[cur][g][t];
                const float gv = gS[cur][g][t];
                const int wt = w * 64 + t;
                const int l  = dir ? (cL - 1 - wt) : wt;
                const float val = (yo + uu * Dd) * (gv / (1.f + __expf(-gv)));
                yout[((long)b * cL + l) * cDM + d] = f2bf(val);
            }
        }

        if (w < cL / 64 - 1) STAGE_WRITE(cur ^ 1);
        __syncthreads();
    }
}

// ---------------------------------------------------------------------------
extern "C" void kernel_launch(void* const* d_in, const int* in_sizes, int n_in,
                              void* d_out, int out_size, void* d_ws, size_t ws_size,
                              hipStream_t stream)
{
    const float* hid   = (const float*)d_in[0];   // (B,L,H)
    const float* inw   = (const float*)d_in[1];   // (2DM,H)
    const float* convw = (const float*)d_in[2];   // (DM,K)
    const float* convb = (const float*)d_in[3];   // (DM)
    const float* xpw   = (const float*)d_in[4];   // (80,DM)
    const float* dtw   = (const float*)d_in[5];   // (DM,R)
    const float* dtb   = (const float*)d_in[6];   // (DM)
    const float* xpbw  = (const float*)d_in[7];
    const float* dtbw  = (const float*)d_in[8];
    const float* dtbb  = (const float*)d_in[9];
    const float* Alog  = (const float*)d_in[10];  // (DM,16)
    const float* Alogb = (const float*)d_in[11];
    const float* Dv    = (const float*)d_in[12];
    const float* Dbv   = (const float*)d_in[13];
    const float* outw  = (const float*)d_in[14];  // (H,DM)
    float* out = (float*)d_out;                   // (B,L,H)

    float* ws = (float*)d_ws;
    const long S = (long)cB * cDM * cL;           // 3,145,728
    float* xbuf   = ws;                // x, then delta_f
    float* gate   = ws + S;
    float* conv   = ws + 2 * S;        // u fp32 (b,d,l)
    float* deltab = ws + 3 * S;
    float* ssms   = ws + 4 * S;        // (B,L,160) fp32
    u16* up0      = (u16*)(ssms + (long)cB * cL * cPS);
    u16* convT_b  = up0;                              // S u16; later yf
    u16* ts2_b    = up0 + S;                          // 2*B*L*64 = 262,144
    u16* xpw2_b   = ts2_b + (long)2 * cB * cL * 64;   // 160*DM stacked
    u16* dtw2_b   = xpw2_b + (long)cPS * cDM;         // 2*DM*64 stacked
    u16* outw_b   = dtw2_b + (long)2 * cDM * 64;      // H*DM
    u16* pool2    = outw_b + (long)cH * cDM;          // 3,932,160 u16
    u16* inw_b    = pool2;                            // 2*DM*H (phase 1)
    u16* hid_b    = pool2 + (long)2 * cDM * cH;       // B*L*H  (phase 1)
    u16* yf_b     = convT_b;                          // phase 2 (after x_proj)
    u16* yb_b     = pool2;                            // phase 2 (after in_proj)

    const dim3 blk(256);

    // 0. dtype converts (weights stacked for fused GEMMs)
    f2b_kernel<<<1024, blk, 0, stream>>>(hid,  hid_b,  (long)cB * cL * cH);
    f2b_kernel<<<1024, blk, 0, stream>>>(inw,  inw_b,  (long)2 * cDM * cH);
    f2b_kernel<<<480,  blk, 0, stream>>>(xpw,  xpw2_b, (long)80 * cDM);
    f2b_kernel<<<480,  blk, 0, stream>>>(xpbw, xpw2_b + (long)80 * cDM, (long)80 * cDM);
    f2b_kernel<<<1024, blk, 0, stream>>>(outw, outw_b, (long)cH * cDM);
    padw_kernel<<<384, blk, 0, stream>>>(dtw,  dtw2_b,  cDM);
    padw_kernel<<<384, blk, 0, stream>>>(dtbw, dtw2_b + (long)cDM * 64, cDM);

    // split-K atomic targets must be zeroed
    hipMemsetAsync(ssms, 0, (long)cB * cL * cPS * sizeof(float), stream);
    hipMemsetAsync(out, 0, (long)out_size * sizeof(float), stream);

    // 1. in_proj (M=3072, N=L, K=H), split x | gate
    gemm_mfma<0><<<dim3(cL / 128, (2 * cDM) / 128, cB), blk, 0, stream>>>(
        inw_b, hid_b, nullptr, xbuf, gate, nullptr, nullptr,
        cL, cH, cH, cH, cL, 0L, (long)cL * cH, (long)cDM * cL, cDM, 1);

    // 2. causal conv + SiLU (tiled; both outputs coalesced)
    conv_silu_t<<<dim3(cL / 32, cDM / 32, cB), blk, 0, stream>>>(
        xbuf, convw, convb, conv, convT_b);

    // 3. fused x_proj fwd+bwd: M=L, N=160, K=DM, split-K=8
    gemm_mfma<2><<<dim3(2, cL / 128, cB * 8), blk, 0, stream>>>(
        convT_b, xpw2_b, nullptr, ssms, nullptr, nullptr, nullptr,
        cPS, cDM, cDM, cDM, cPS, (long)cL * cDM, 0L, (long)cL * cPS, 1 << 30, 8);

    // 4. ts slices -> padded bf16 (2,B,L,64)
    tspad_kernel<<<1024, blk, 0, stream>>>(ssms, ts2_b);

    // 5. fused delta fwd+bwd: M=3072, N=L, K=64; B/bias switch at m=1536
    gemm_mfma<1><<<dim3(cL / 128, (2 * cDM) / 128, cB), blk, 0, stream>>>(
        dtw2_b, ts2_b, ts2_b + (long)cB * cL * 64,
        xbuf /*delta_f*/, deltab, dtb, dtbb,
        cL, 64, 64, 64, cL, 0L, (long)cL * 64, (long)cDM * cL, cDM, 1);

    // 6. fused bidirectional scan (LDS windows, plain bf16 stores per dir)
    scan3_kernel<<<dim3(cDM / 16, cB, 2), blk, 0, stream>>>(
        conv, gate, xbuf /*delta_f*/, deltab, ssms,
        Alog, Alogb, Dv, Dbv, yf_b, yb_b);

    // 7. combine: yf += yb (in place, bf16, 16B/thread)
    comb_kernel<<<(int)(S / 8 / 256), blk, 0, stream>>>(yf_b, yb_b, S / 8);

    // 8. out_proj: M=L, N=H, K=DM, split-K=2 (out zeroed above)
    gemm_mfma<2><<<dim3(cH / 128, cL / 128, cB * 2), blk, 0, stream>>>(
        yf_b, outw_b, nullptr, out, nullptr, nullptr, nullptr,
        cH, cDM, cDM, cDM, cH, (long)cL * cDM, 0L, (long)cL * cH, 1 << 30, 2);
}